// Round 6
// baseline (301.977 us; speedup 1.0000x reference)
//
#include <hip/hip_runtime.h>
#include <math.h>

// PixelEachSubstitutor fused implementation for MI355X (gfx950) — round 6.
//
// Algebraic folds (exact):
//  (1) Encoder seq = 9 real rows + 72 zero rows -> 9x9 attention + shared row.
//  (2) M_enc = Wq^T Wk * log2e/sqrt(11): scores direct from features, exp2 domain.
//  (3) WVO = Wo @ Wv: attention emits post-out-proj rows directly.
//  (4) G_k/G_v = F @ Wk_ca^T / Wv_ca^T: cross-attn K/V straight from encoder out.
//  (5) Decoder self-attn pixel-independent -> y1, qca (pre-scaled by log2e).
//  (6) Decoder tail TRANSPOSED: lane t owns row t; LN2/FF/LN3 stats computed as
//      7 in-register dots + moment identities (tables staged in LDS). ZERO
//      cross-lane ops in the tail. (r4's swizzle tail and r5's shfl tail both
//      regressed: dependent lgkmcnt-chains serialize the whole LDS FIFO.)
//
// Structure: 4 independent waves/block, 1 pixel/wave, private LDS slice,
// wave-local fences only. Cross-attn K/V fully register-resident.

#define LOG2E 1.4426950408889634f

// Per-wave LDS slice layout (floats, 16B-aligned):
#define F9o   0     // 9 x 12
#define Go    112   // 9 x 12
#define VOTo  224   // 11 x 12  (transposed VO: VOT[c][s])
#define SCo   368   // rows 0..8 scores->weights; row 9 = ones/81 @ +108; inv @ +120
#define ZRo   512   // 10 x 12
#define FETo  640   // 11 x 12  (transposed encoder out: FET[c][t])
#define OCo   0     // 10 x 32 oca, overlays F9/G/VOT (dead by then)
#define STo   0     // tail stats: 5 arrays stride 16 (overlays dead oca)
#define HDo   96    // head hidden [80]
#define ZTo   384   // z rows, 10 x 36 (stride 36: bank-spread row reads)
#define SLICE 784

__device__ __forceinline__ void wsync() {
  asm volatile("s_waitcnt lgkmcnt(0)" ::: "memory");
}

// ---------------------------------------------------------------------------
// Precompute kernel (2 independent blocks, 256 threads each).
// ---------------------------------------------------------------------------
__global__ __launch_bounds__(256) void precompute_kernel(
    const float* __restrict__ Vf,          // (10,32)
    const float* __restrict__ enc_in,      // (33,11)
    const float* __restrict__ enc_outw,    // (11,11)
    const float* __restrict__ ffV_w,       // (32,81)
    const float* __restrict__ dec_sa_in,   // (96,32)
    const float* __restrict__ dec_sa_out,  // (32,32)
    const float* __restrict__ dec_ln1,     // (32)
    const float* __restrict__ dec_ca_in,   // (96,32)
    const float* __restrict__ dec_ln2v, const float* __restrict__ dec_lin1,
    const float* __restrict__ dec_lin2, const float* __restrict__ dec_ln3v,
    float* __restrict__ M_enc, float* __restrict__ WVO,
    float* __restrict__ G_k, float* __restrict__ G_v,
    float* __restrict__ y1, float* __restrict__ qca,
    float* __restrict__ t4w, float* __restrict__ tabs)
{
  const int tid = threadIdx.x;

  if (blockIdx.x == 0) {
    const float rs11 = 0.3015113445777636f;  // 1/sqrt(11)
    // M_enc = (Wq^T Wk)*log2e/sqrt(11); WVO = Wo@Wv
    for (int idx = tid; idx < 121; idx += 256) {
      int c = idx / 11, cp = idx - c * 11;
      float sm = 0.f, sv = 0.f;
      for (int i = 0; i < 11; ++i) {
        sm += enc_in[i * 11 + c] * enc_in[(11 + i) * 11 + cp];
        sv += enc_outw[c * 11 + i] * enc_in[(22 + i) * 11 + cp];
      }
      M_enc[idx] = sm * rs11 * LOG2E;
      WVO[idx] = sv;
    }
    // pad M_enc/WVO tails so staging copies defined values
    if (tid >= 121 && tid < 128) { M_enc[tid] = 0.f; WVO[tid] = 0.f; }

    // F[t][j]: t<9 -> ffV_w[j][t]; F[9][j] = sum_{t>=9} ffV_w[j][t]
    __shared__ float Fsh[320];
    for (int idx = tid; idx < 288; idx += 256) {
      int t = idx >> 5, j = idx & 31;
      Fsh[idx] = ffV_w[j * 81 + t];
    }
    if (tid < 32) {
      float s = 0.f;
      for (int t = 9; t < 81; ++t) s += ffV_w[tid * 81 + t];
      Fsh[288 + tid] = s;
    }
    __syncthreads();

    for (int idx = tid; idx < 640; idx += 256) {
      int which = idx >= 320;
      int r = idx - 320 * which;
      int t = r >> 5, h = r & 31;
      const float* w = dec_ca_in + ((which ? 64 : 32) + h) * 32;
      float s = 0.f;
      for (int j = 0; j < 32; ++j) s += Fsh[t * 32 + j] * w[j];
      (which ? G_v : G_k)[r] = s;
    }

    // Tail constants: t4[c]={w2, w2*l1, l2, w3}; tables w2/w2l1/w2sq/w2l2;
    // scalars tabs[128..133] = {Sw2l1, Sw2, Sw2sq, Sw2l2, Sl2, Sl2sq}
    if (tid < 32) {
      float w2 = dec_ln2v[tid], l1 = dec_lin1[tid];
      float l2 = dec_lin2[tid], w3 = dec_ln3v[tid];
      ((float4*)t4w)[tid] = make_float4(w2, w2 * l1, l2, w3);
      tabs[tid] = w2;
      tabs[32 + tid] = w2 * l1;
      tabs[64 + tid] = w2 * w2;
      tabs[96 + tid] = w2 * l2;
    } else if (tid == 32) {
      float a = 0, b = 0, c2 = 0, d = 0, e = 0, f = 0;
      for (int c = 0; c < 32; ++c) {
        float w2 = dec_ln2v[c], l2 = dec_lin2[c];
        a += w2 * dec_lin1[c]; b += w2; c2 += w2 * w2;
        d += w2 * l2; e += l2; f += l2 * l2;
      }
      tabs[128] = a; tabs[129] = b; tabs[130] = c2;
      tabs[131] = d; tabs[132] = e; tabs[133] = f;
    }
  } else {
    // Decoder self-attention on broadcast V_feature (pixel-independent).
    __shared__ float qsa[320], ksa[320], vsa[320], osa[320], zb[320];
    __shared__ float mu[16], rstd[16];

    for (int idx = tid; idx < 960; idx += 256) {
      int m = idx / 320, r = idx - m * 320;
      int t = r >> 5, h = r & 31;
      const float* w = dec_sa_in + (m * 32 + h) * 32;
      const float* yr = Vf + t * 32;
      float s = 0.f;
#pragma unroll
      for (int j = 0; j < 32; ++j) s += yr[j] * w[j];
      (m == 0 ? qsa : m == 1 ? ksa : vsa)[r] = s;
    }
    __syncthreads();

    for (int idx = tid; idx < 320; idx += 256) {  // nhead=32, hd=1
      int h = idx & 31;
      float q = qsa[idx];
      float sc[10];
      float mx = -1e30f;
#pragma unroll
      for (int s = 0; s < 10; ++s) { sc[s] = q * ksa[s * 32 + h]; mx = fmaxf(mx, sc[s]); }
      float den = 0.f, acc = 0.f;
#pragma unroll
      for (int s = 0; s < 10; ++s) {
        float e = __expf(sc[s] - mx);
        den += e;
        acc += e * vsa[s * 32 + h];
      }
      osa[idx] = acc / den;
    }
    __syncthreads();

    for (int idx = tid; idx < 320; idx += 256) {
      int t = idx >> 5, c = idx & 31;
      float s = 0.f;
#pragma unroll
      for (int h = 0; h < 32; ++h) s += osa[t * 32 + h] * dec_sa_out[c * 32 + h];
      zb[idx] = Vf[idx] + s;
    }
    __syncthreads();

    if (tid < 10) {
      float s1 = 0.f, s2 = 0.f;
      for (int c = 0; c < 32; ++c) { float z = zb[tid * 32 + c]; s1 += z; s2 += z * z; }
      float m = s1 * (1.f / 32.f);
      mu[tid] = m;
      rstd[tid] = 1.f / sqrtf(s2 * (1.f / 32.f) - m * m + 1e-5f);
    }
    __syncthreads();

    for (int idx = tid; idx < 320; idx += 256) {
      int t = idx >> 5, c = idx & 31;
      float v = (zb[idx] - mu[t]) * rstd[t] * dec_ln1[c];
      y1[idx] = v;
      zb[idx] = v;
    }
    __syncthreads();

    for (int idx = tid; idx < 320; idx += 256) {  // qca = (y1 @ Wq_ca.T)*log2e
      int t = idx >> 5, h = idx & 31;
      const float* w = dec_ca_in + h * 32;
      float s = 0.f;
#pragma unroll
      for (int j = 0; j < 32; ++j) s += zb[t * 32 + j] * w[j];
      qca[idx] = s * LOG2E;
    }
  }
}

// ---------------------------------------------------------------------------
// Main kernel.
// ---------------------------------------------------------------------------
__global__ __launch_bounds__(256) void pixel_main_kernel(
    const float* __restrict__ x,
    const float* __restrict__ M_enc, const float* __restrict__ WVO,
    const float* __restrict__ enc_lin1, const float* __restrict__ enc_lin2,
    const float* __restrict__ enc_ln1, const float* __restrict__ enc_ln2,
    const float* __restrict__ G_k, const float* __restrict__ G_v,
    const float* __restrict__ y1g, const float* __restrict__ qcag,
    const float* __restrict__ dec_ca_out,
    const float* __restrict__ W_d0, const float* __restrict__ W_d1,
    const float* __restrict__ t4g, const float* __restrict__ tabsg,
    float* __restrict__ out)
{
  __shared__ __align__(16) float sh[4 * SLICE + 384];
  float* bc = sh + 4 * SLICE;  // block-common: M_enc @0, WVO @128, tables @256
  for (int i = threadIdx.x; i < 128; i += 256) {
    bc[i] = M_enc[i];
    bc[128 + i] = WVO[i];
    bc[256 + i] = tabsg[i];
  }
  __syncthreads();  // only block-wide barrier (kernel start, all waves present)

  const int wave = threadIdx.x >> 6;
  const int lane = threadIdx.x & 63;
  float* ls = sh + wave * SLICE;

  const int p = blockIdx.x * 4 + wave;
  const int n = p / 900;
  const int rem = p - n * 900;
  const int pi = rem / 30, pj = rem - (rem / 30) * 30;

  // ---- P1: 9 real feature rows (stride 12) + SC row 9 = ones/81 ----
  for (int idx = lane; idx < 99; idx += 64) {
    int t = idx / 11, c = idx - t * 11;
    float val = 1.0f;
    if (c < 10) {
      int di = t / 3, dj = t - (t / 3) * 3;
      int ii = pi + di - 1, jj = pj + dj - 1;
      val = (ii >= 0 && ii < 30 && jj >= 0 && jj < 30)
                ? x[((n * 10 + c) * 30 + ii) * 30 + jj] : 0.0f;
    }
    ls[F9o + t * 12 + c] = val;
  }
  if (lane < 12) ls[SCo + 108 + lane] = (lane < 9) ? (1.0f / 81.0f) : 0.0f;
  wsync();

  // ---- P2: G[s][c] = f9[s].M_enc[c,:], VOT[c][s] = f9[s].WVO[c,:] ----
  for (int idx = lane; idx < 99; idx += 64) {
    int s = idx / 11, c = idx - (idx / 11) * 11;
    const float4* fr = (const float4*)(ls + F9o + s * 12);
    float4 f0 = fr[0], f1 = fr[1], f2 = fr[2];
    float fv[11] = {f0.x, f0.y, f0.z, f0.w, f1.x, f1.y, f1.z, f1.w, f2.x, f2.y, f2.z};
    const float* Mr = bc + c * 11;
    const float* Wr = bc + 128 + c * 11;
    float ag = 0.f, av = 0.f;
#pragma unroll
    for (int cp = 0; cp < 11; ++cp) { ag += Mr[cp] * fv[cp]; av += Wr[cp] * fv[cp]; }
    ls[Go + s * 12 + c] = ag;
    ls[VOTo + c * 12 + s] = av;
  }
  wsync();

  // ---- P2b: scores (log2 domain) sc[t][s] = f9[t].g[s] ----
  for (int idx = lane; idx < 81; idx += 64) {
    int t = idx / 9, s = idx - (idx / 9) * 9;
    const float4* fr = (const float4*)(ls + F9o + t * 12);
    const float4* gr = (const float4*)(ls + Go + s * 12);
    float4 f0 = fr[0], f1 = fr[1], f2 = fr[2];
    float4 g0 = gr[0], g1 = gr[1], g2 = gr[2];
    float a = f0.x * g0.x + f0.y * g0.y + f0.z * g0.z + f0.w * g0.w
            + f1.x * g1.x + f1.y * g1.y + f1.z * g1.z + f1.w * g1.w
            + f2.x * g2.x + f2.y * g2.y + f2.z * g2.z;
    ls[SCo + t * 12 + s] = a;
  }
  wsync();

  // ---- P3s: per-row softmax weights (lanes 0-8); 72 padded keys at score 0 ----
  if (lane < 9) {
    const float4* sr = (const float4*)(ls + SCo + lane * 12);
    float4 s0 = sr[0], s1 = sr[1];
    float sc[9] = {s0.x, s0.y, s0.z, s0.w, s1.x, s1.y, s1.z, s1.w,
                   ls[SCo + lane * 12 + 8]};
    float mx = 0.0f;
#pragma unroll
    for (int s = 0; s < 9; ++s) mx = fmaxf(mx, sc[s]);
    float den = 72.0f * exp2f(-mx);
    float e[9];
#pragma unroll
    for (int s = 0; s < 9; ++s) { e[s] = exp2f(sc[s] - mx); den += e[s]; }
    float4* dst = (float4*)(ls + SCo + lane * 12);
    dst[0] = make_float4(e[0], e[1], e[2], e[3]);
    dst[1] = make_float4(e[4], e[5], e[6], e[7]);
    dst[2] = make_float4(e[8], 0.f, 0.f, 0.f);
    ls[SCo + 120 + lane] = __builtin_amdgcn_rcpf(den);
  }
  wsync();

  // ---- P3d: ZR rows = softmax-weighted VOT dot + residual; row 9 shared ----
  for (int idx = lane; idx < 110; idx += 64) {
    int t = idx / 11, c = idx - (idx / 11) * 11;
    const float4* wr = (const float4*)(ls + SCo + t * 12);
    const float4* vr = (const float4*)(ls + VOTo + c * 12);
    float4 w0 = wr[0], w1 = wr[1], w2q = wr[2];
    float4 v0 = vr[0], v1 = vr[1], v2 = vr[2];
    float a = w0.x * v0.x + w0.y * v0.y + w0.z * v0.z + w0.w * v0.w
            + w1.x * v1.x + w1.y * v1.y + w1.z * v1.z + w1.w * v1.w
            + w2q.x * v2.x;
    if (t < 9) a = a * ls[SCo + 120 + t] + ls[F9o + t * 12 + c];
    ls[ZRo + t * 12 + c] = a;
  }
  wsync();

  // ---- P4s: per-row LN1+FF+LN2 (lanes 0-9) -> FET[c][t] (transposed) ----
  if (lane < 10) {
    const float4* zr = (const float4*)(ls + ZRo + lane * 12);
    float4 z0 = zr[0], z1 = zr[1], z2q = zr[2];
    float row[11] = {z0.x, z0.y, z0.z, z0.w, z1.x, z1.y, z1.z, z1.w,
                     z2q.x, z2q.y, z2q.z};
    float s1 = 0.f, s2 = 0.f;
#pragma unroll
    for (int c = 0; c < 11; ++c) { s1 += row[c]; s2 += row[c] * row[c]; }
    float mu = s1 * (1.0f / 11.0f);
    float rs = __builtin_amdgcn_rsqf(s2 * (1.0f / 11.0f) - mu * mu + 1e-5f);
    float h = 0.f;
#pragma unroll
    for (int c = 0; c < 11; ++c) {
      row[c] = (row[c] - mu) * rs * enc_ln1[c];
      h += row[c] * enc_lin1[c];
    }
    h = fmaxf(h, 0.f);
    float t1 = 0.f, t2 = 0.f;
#pragma unroll
    for (int c = 0; c < 11; ++c) {
      row[c] += h * enc_lin2[c];
      t1 += row[c]; t2 += row[c] * row[c];
    }
    float mu2 = t1 * (1.0f / 11.0f);
    float rs2 = __builtin_amdgcn_rsqf(t2 * (1.0f / 11.0f) - mu2 * mu2 + 1e-5f);
#pragma unroll
    for (int c = 0; c < 11; ++c)
      ls[FETo + c * 12 + lane] = (row[c] - mu2) * rs2 * enc_ln2[c];
  }
  wsync();

  // ---- P5: per-lane K-row (grp0) / V-row (grp1) over 11 mem-rows, in regs ----
  const int hh = lane & 31, grp = lane >> 5;
  float kv[11];
  {
    const float* Gb = grp ? G_v : G_k;
    float gr[10];
#pragma unroll
    for (int t = 0; t < 10; ++t) gr[t] = Gb[t * 32 + hh];
#pragma unroll
    for (int cc = 0; cc < 11; ++cc) {
      const float4* fr = (const float4*)(ls + FETo + cc * 12);
      float4 a = fr[0], b4 = fr[1], c4 = fr[2];
      float fe[10] = {a.x, a.y, a.z, a.w, b4.x, b4.y, b4.z, b4.w, c4.x, c4.y};
      float s = 0.f;
#pragma unroll
      for (int t = 0; t < 10; ++t) s += fe[t] * gr[t];
      kv[cc] = s;
    }
  }
  // exchange halves: every lane ends with kk = K-row, vv = V-row for head hh
  float kk[11], vv[11];
#pragma unroll
  for (int cc = 0; cc < 11; ++cc) {
    float o = __shfl_xor(kv[cc], 32);
    kk[cc] = grp ? o : kv[cc];
    vv[cc] = grp ? kv[cc] : o;
  }

  // ---- P6: cross-attn (32 heads dim-1), register-only -> oca @ OCo ----
#pragma unroll
  for (int i = 0; i < 5; ++i) {
    int t = grp * 5 + i;
    float q = qcag[t * 32 + hh];  // pre-scaled by log2e
    float sc[11];
    float mx = q * kk[0];
    sc[0] = mx;
#pragma unroll
    for (int s = 1; s < 11; ++s) { sc[s] = q * kk[s]; mx = fmaxf(mx, sc[s]); }
    float den = 0.f, acc = 0.f;
#pragma unroll
    for (int s = 0; s < 11; ++s) {
      float e = exp2f(sc[s] - mx);
      den += e;
      acc += e * vv[s];
    }
    ls[OCo + t * 32 + hh] = acc * __builtin_amdgcn_rcpf(den);
  }
  wsync();

  // ---- T1: out-proj + residual -> z[t][c] @ ZTo (stride 36) ----
  const int c = hh;
  {
    const float4* wrow = (const float4*)(dec_ca_out + c * 32);
#pragma unroll
    for (int k = 0; k < 5; ++k) {
      const int t = 2 * k + grp;
      float z = y1g[t * 32 + c];
      const float4* orow = (const float4*)(ls + OCo + t * 32);
#pragma unroll
      for (int h4 = 0; h4 < 8; ++h4) {
        float4 o4 = orow[h4];
        float4 w4 = wrow[h4];
        z += o4.x * w4.x + o4.y * w4.y + o4.z * w4.z + o4.w * w4.w;
      }
      ls[ZTo + t * 36 + c] = z;
    }
  }
  wsync();

  // ---- T2: lane t<10 computes ALL tail stats in registers (no cross-lane) ----
  if (lane < 10) {
    const float4* zr    = (const float4*)(ls + ZTo + lane * 36);
    const float4* tw2   = (const float4*)(bc + 256);
    const float4* tw2l1 = (const float4*)(bc + 288);
    const float4* tw2sq = (const float4*)(bc + 320);
    const float4* tw2l2 = (const float4*)(bc + 352);
    float D1 = 0, D2 = 0, D3 = 0, D4 = 0, D5 = 0, D6 = 0, D7 = 0;
#pragma unroll
    for (int q = 0; q < 8; ++q) {
      float4 z4 = zr[q], a4 = tw2[q], b4 = tw2l1[q], s4 = tw2sq[q], d4 = tw2l2[q];
#define ACC(zc, ac, bcm, scm, dcm)                                         \
      { float zz = zc; D1 += zz; D2 += zz * zz; D3 += zz * bcm;            \
        D4 += zz * ac; D5 += zz * scm; D6 += zz * zz * scm; D7 += zz * dcm; }
      ACC(z4.x, a4.x, b4.x, s4.x, d4.x)
      ACC(z4.y, a4.y, b4.y, s4.y, d4.y)
      ACC(z4.z, a4.z, b4.z, s4.z, d4.z)
      ACC(z4.w, a4.w, b4.w, s4.w, d4.w)
#undef ACC
    }
    const float Sw2l1 = tabsg[128], Sw2 = tabsg[129], Sw2sq = tabsg[130],
                Sw2l2 = tabsg[131], Sl2 = tabsg[132], Sl2sq = tabsg[133];
    const float inv32 = 1.0f / 32.0f;
    float mu = D1 * inv32;
    float rs = __builtin_amdgcn_rsqf(D2 * inv32 - mu * mu + 1e-5f);
    float h1 = fmaxf(rs * (D3 - mu * Sw2l1), 0.f);
    float sz2 = rs * (D4 - mu * Sw2);
    float sz2sq = rs * rs * (D6 - 2.f * mu * D5 + mu * mu * Sw2sq);
    float sz2l2 = rs * (D7 - mu * Sw2l2);
    float sz3 = sz2 + h1 * Sl2;
    float sz3sq = sz2sq + 2.f * h1 * sz2l2 + h1 * h1 * Sl2sq;
    float mu3 = sz3 * inv32;
    float rs3 = __builtin_amdgcn_rsqf(sz3sq * inv32 - mu3 * mu3 + 1e-5f);
    ls[STo + lane] = mu;
    ls[STo + 16 + lane] = rs;
    ls[STo + 32 + lane] = h1;
    ls[STo + 48 + lane] = mu3;
    ls[STo + 64 + lane] = rs3;
  }
  wsync();

  // ---- T3: apply z3n = ((z-mu)*rs*w2 + h1*l2 - mu3)*rs3*w3, in place ----
  {
    const float4 t4 = ((const float4*)t4g)[c];  // {w2, w2*l1, l2, w3}
#pragma unroll
    for (int k = 0; k < 5; ++k) {
      const int t = 2 * k + grp;
      float mu = ls[STo + t], rs = ls[STo + 16 + t], h1 = ls[STo + 32 + t];
      float mu3 = ls[STo + 48 + t], rs3 = ls[STo + 64 + t];
      float z = ls[ZTo + t * 36 + c];
      ls[ZTo + t * 36 + c] = ((z - mu) * rs * t4.x + h1 * t4.z - mu3) * rs3 * t4.w;
    }
  }
  wsync();

  // ---- T5: head layer 1: relu(z3n @ W_d0^T) -> hidden @ HDo ----
  for (int idx = lane; idx < 80; idx += 64) {
    int t = idx >> 3, m = idx & 7;
    const float4* arow = (const float4*)(W_d0 + m * 32);
    const float4* zrow4 = (const float4*)(ls + ZTo + t * 36);
    float d = 0.f;
#pragma unroll
    for (int q4 = 0; q4 < 8; ++q4) {
      float4 a4 = arow[q4];
      float4 z4 = zrow4[q4];
      d += a4.x * z4.x + a4.y * z4.y + a4.z * z4.z + a4.w * z4.w;
    }
    ls[HDo + idx] = fmaxf(d, 0.f);
  }
  wsync();

  // ---- T6: head layer 2 + store ----
  if (lane < 10) {
    float r = 0.f;
#pragma unroll
    for (int m = 0; m < 8; ++m) r += ls[HDo + lane * 8 + m] * W_d1[m];
    out[((n * 10 + lane) * 30 + pi) * 30 + pj] = r;
  }
}

// ---------------------------------------------------------------------------
extern "C" void kernel_launch(void* const* d_in, const int* in_sizes, int n_in,
                              void* d_out, int out_size, void* d_ws, size_t ws_size,
                              hipStream_t stream) {
  (void)in_sizes; (void)n_in; (void)out_size; (void)ws_size;
  const float* x          = (const float*)d_in[0];
  const float* Vf         = (const float*)d_in[1];
  const float* enc_in     = (const float*)d_in[2];
  const float* enc_outw   = (const float*)d_in[3];
  const float* enc_lin1   = (const float*)d_in[4];
  const float* enc_lin2   = (const float*)d_in[5];
  const float* enc_ln1    = (const float*)d_in[6];
  const float* enc_ln2    = (const float*)d_in[7];
  const float* ffV_w      = (const float*)d_in[8];
  const float* dec_sa_in  = (const float*)d_in[9];
  const float* dec_sa_out = (const float*)d_in[10];
  const float* dec_ca_in  = (const float*)d_in[11];
  const float* dec_ca_out = (const float*)d_in[12];
  const float* dec_lin1   = (const float*)d_in[13];
  const float* dec_lin2   = (const float*)d_in[14];
  const float* dec_ln1    = (const float*)d_in[15];
  const float* dec_ln2    = (const float*)d_in[16];
  const float* dec_ln3    = (const float*)d_in[17];
  const float* W_d0       = (const float*)d_in[18];
  const float* W_d1       = (const float*)d_in[19];
  float* out = (float*)d_out;

  float* ws    = (float*)d_ws;
  float* M_enc = ws;            // 128
  float* WVO   = ws + 128;      // 128
  float* G_k   = ws + 256;      // 320
  float* G_v   = ws + 576;      // 320
  float* y1    = ws + 896;      // 320
  float* qca   = ws + 1216;     // 320
  float* t4w   = ws + 1536;     // 128
  float* tabs  = ws + 1664;     // 134 -> pad 160 (total 1824 floats = 7.1 KiB)

  hipLaunchKernelGGL(precompute_kernel, dim3(2), dim3(256), 0, stream,
                     Vf, enc_in, enc_outw, ffV_w, dec_sa_in, dec_sa_out,
                     dec_ln1, dec_ca_in, dec_ln2, dec_lin1, dec_lin2, dec_ln3,
                     M_enc, WVO, G_k, G_v, y1, qca, t4w, tabs);

  hipLaunchKernelGGL(pixel_main_kernel, dim3(3600), dim3(256), 0, stream,
                     x, M_enc, WVO, enc_lin1, enc_lin2, enc_ln1, enc_ln2,
                     G_k, G_v, y1, qca, dec_ca_out, W_d0, W_d1, t4w, tabs, out);
}

// Round 7
// 171.065 us; speedup vs baseline: 1.7653x; 1.7653x over previous
//
#include <hip/hip_runtime.h>
#include <math.h>

// PixelEachSubstitutor fused implementation for MI355X (gfx950) — round 7.
// Base: round-3 kernel (93 us, best measured). ONE isolated change:
// cross-attention K/V computed in REGISTERS (r4's proven P5/P6 structure),
// deleting the 704-float KC/VC LDS buffers -> LDS/block 22016 -> 11264 B.
// Everything else is verbatim round-3 (phases, tail, precompute, math idioms).
//
// Algebraic folds (exact), unchanged:
//  (1) Encoder seq = 9 real rows + 72 zero rows -> 9x9 attention + shared row.
//  (2) M_enc = Wq^T Wk / sqrt(11): scores direct from features.
//  (3) WVO = Wo @ Wv: attention emits post-out-proj rows directly.
//  (4) G_k/G_v = F @ Wk_ca^T / Wv_ca^T: cross-attn K/V straight from encoder out.
//  (5) Decoder self-attn pixel-independent -> y1, qca precomputed once.

__device__ __forceinline__ float gsum32(float v) {
#pragma unroll
  for (int m = 16; m > 0; m >>= 1) v += __shfl_xor(v, m, 32);
  return v;
}

__device__ __forceinline__ void wsync() {
  asm volatile("s_waitcnt lgkmcnt(0)" ::: "memory");
}

// ---------------------------------------------------------------------------
// Precompute kernel (2 independent blocks, 256 threads each) — verbatim r3.
// ---------------------------------------------------------------------------
__global__ __launch_bounds__(256) void precompute_kernel(
    const float* __restrict__ Vf,          // (10,32)
    const float* __restrict__ enc_in,      // (33,11)
    const float* __restrict__ enc_outw,    // (11,11)
    const float* __restrict__ ffV_w,       // (32,81)
    const float* __restrict__ dec_sa_in,   // (96,32)
    const float* __restrict__ dec_sa_out,  // (32,32)
    const float* __restrict__ dec_ln1,     // (32)
    const float* __restrict__ dec_ca_in,   // (96,32)
    float* __restrict__ M_enc, float* __restrict__ WVO,
    float* __restrict__ G_k, float* __restrict__ G_v,
    float* __restrict__ y1, float* __restrict__ qca)
{
  const int tid = threadIdx.x;

  if (blockIdx.x == 0) {
    const float rs11 = 0.3015113445777636f;  // 1/sqrt(11)
    for (int idx = tid; idx < 121; idx += 256) {
      int c = idx / 11, cp = idx - c * 11;
      float sm = 0.f, sv = 0.f;
      for (int i = 0; i < 11; ++i) {
        sm += enc_in[i * 11 + c] * enc_in[(11 + i) * 11 + cp];
        sv += enc_outw[c * 11 + i] * enc_in[(22 + i) * 11 + cp];
      }
      M_enc[idx] = sm * rs11;
      WVO[idx] = sv;
    }

    __shared__ float Fsh[320];
    for (int idx = tid; idx < 288; idx += 256) {
      int t = idx >> 5, j = idx & 31;
      Fsh[idx] = ffV_w[j * 81 + t];
    }
    if (tid < 32) {
      float s = 0.f;
      for (int t = 9; t < 81; ++t) s += ffV_w[tid * 81 + t];
      Fsh[288 + tid] = s;
    }
    __syncthreads();

    for (int idx = tid; idx < 640; idx += 256) {
      int which = idx >= 320;
      int r = idx - 320 * which;
      int t = r >> 5, h = r & 31;
      const float* w = dec_ca_in + ((which ? 64 : 32) + h) * 32;
      float s = 0.f;
      for (int j = 0; j < 32; ++j) s += Fsh[t * 32 + j] * w[j];
      (which ? G_v : G_k)[r] = s;
    }
  } else {
    __shared__ float qsa[320], ksa[320], vsa[320], osa[320], zb[320];
    __shared__ float mu[16], rstd[16];

    for (int idx = tid; idx < 960; idx += 256) {
      int m = idx / 320, r = idx - m * 320;
      int t = r >> 5, h = r & 31;
      const float* w = dec_sa_in + (m * 32 + h) * 32;
      const float* yr = Vf + t * 32;
      float s = 0.f;
#pragma unroll
      for (int j = 0; j < 32; ++j) s += yr[j] * w[j];
      (m == 0 ? qsa : m == 1 ? ksa : vsa)[r] = s;
    }
    __syncthreads();

    for (int idx = tid; idx < 320; idx += 256) {  // nhead=32, hd=1
      int h = idx & 31;
      float q = qsa[idx];
      float sc[10];
      float mx = -1e30f;
#pragma unroll
      for (int s = 0; s < 10; ++s) { sc[s] = q * ksa[s * 32 + h]; mx = fmaxf(mx, sc[s]); }
      float den = 0.f, acc = 0.f;
#pragma unroll
      for (int s = 0; s < 10; ++s) {
        float e = __expf(sc[s] - mx);
        den += e;
        acc += e * vsa[s * 32 + h];
      }
      osa[idx] = acc / den;
    }
    __syncthreads();

    for (int idx = tid; idx < 320; idx += 256) {
      int t = idx >> 5, c = idx & 31;
      float s = 0.f;
#pragma unroll
      for (int h = 0; h < 32; ++h) s += osa[t * 32 + h] * dec_sa_out[c * 32 + h];
      zb[idx] = Vf[idx] + s;
    }
    __syncthreads();

    if (tid < 10) {
      float s1 = 0.f, s2 = 0.f;
      for (int c = 0; c < 32; ++c) { float z = zb[tid * 32 + c]; s1 += z; s2 += z * z; }
      float m = s1 * (1.f / 32.f);
      mu[tid] = m;
      rstd[tid] = 1.f / sqrtf(s2 * (1.f / 32.f) - m * m + 1e-5f);
    }
    __syncthreads();

    for (int idx = tid; idx < 320; idx += 256) {
      int t = idx >> 5, c = idx & 31;
      float v = (zb[idx] - mu[t]) * rstd[t] * dec_ln1[c];
      y1[idx] = v;
      zb[idx] = v;
    }
    __syncthreads();

    for (int idx = tid; idx < 320; idx += 256) {  // qca = y1 @ Wq_ca.T
      int t = idx >> 5, h = idx & 31;
      const float* w = dec_ca_in + h * 32;
      float s = 0.f;
#pragma unroll
      for (int j = 0; j < 32; ++j) s += zb[t * 32 + j] * w[j];
      qca[idx] = s;
    }
  }
}

// ---------------------------------------------------------------------------
// Main kernel: 4 independent waves/block, 1 pixel/wave. Per-wave LDS slice:
//   F9 0..98 | G 112..210 | VO 224..322 | SC 336..425 (+inv @ +81)
//   ZR 432..541 | FET 544..675 (11 rows x stride 12, [c][t])
//   OC = 0..319 (reuses dead F9/G/VO), ZB = 320..639 (dead SC/ZR, FET dead by P7a)
// ---------------------------------------------------------------------------
#define SLICE 704

__global__ __launch_bounds__(256) void pixel_main_kernel(
    const float* __restrict__ x,          // (16,10,30,30)
    const float* __restrict__ M_enc, const float* __restrict__ WVO,
    const float* __restrict__ enc_lin1, const float* __restrict__ enc_lin2,
    const float* __restrict__ enc_ln1, const float* __restrict__ enc_ln2,
    const float* __restrict__ G_k, const float* __restrict__ G_v,
    const float* __restrict__ y1g, const float* __restrict__ qcag,
    const float* __restrict__ dec_ca_out,  // (32,32): row c = WoT column c
    const float* __restrict__ dec_lin1, const float* __restrict__ dec_lin2,
    const float* __restrict__ dec_ln2v, const float* __restrict__ dec_ln3v,
    const float* __restrict__ W_d0, const float* __restrict__ W_d1,
    float* __restrict__ out)
{
  __shared__ __align__(16) float sh[4 * SLICE];
  const int wave = threadIdx.x >> 6;
  const int lane = threadIdx.x & 63;
  float* ls = sh + wave * SLICE;
  const int F9 = 0, G = 112, VO = 224, SC = 336, ZR = 432, FET = 544;
  const int OC = 0, ZB = 320;

  const int p = blockIdx.x * 4 + wave;
  const int n = p / 900;
  const int rem = p - n * 900;
  const int pi = rem / 30, pj = rem - (rem / 30) * 30;

  // P1: build 9 real feature rows f9[t][c]
  for (int idx = lane; idx < 99; idx += 64) {
    int t = idx / 11, c = idx - t * 11;
    float val = 1.0f;
    if (c < 10) {
      int di = t / 3, dj = t - (t / 3) * 3;
      int ii = pi + di - 1, jj = pj + dj - 1;
      val = (ii >= 0 && ii < 30 && jj >= 0 && jj < 30)
                ? x[((n * 10 + c) * 30 + ii) * 30 + jj] : 0.0f;
    }
    ls[F9 + idx] = val;
  }
  wsync();

  // P2: g = f9 @ M_enc^T, vo = f9 @ WVO^T
  for (int idx = lane; idx < 99; idx += 64) {
    int s = idx / 11, c = idx - (idx / 11) * 11;
    const float* Mr = M_enc + c * 11;
    const float* Wr = WVO + c * 11;
    float ag = 0.f, av = 0.f;
#pragma unroll
    for (int cp = 0; cp < 11; ++cp) {
      float fv = ls[F9 + s * 11 + cp];
      ag += Mr[cp] * fv;
      av += Wr[cp] * fv;
    }
    ls[G + idx] = ag;
    ls[VO + idx] = av;
  }
  wsync();

  // P2b: scores sc[t][s] = f9[t] . g[s]
  for (int idx = lane; idx < 81; idx += 64) {
    int t = idx / 9, s = idx - (idx / 9) * 9;
    float a = 0.f;
#pragma unroll
    for (int c = 0; c < 11; ++c) a += ls[F9 + t * 11 + c] * ls[G + s * 11 + c];
    ls[SC + idx] = a;
  }
  wsync();

  // P3s: per-row softmax in registers (lanes 0-8); padded keys: 72*exp(-mx)
  if (lane < 9) {
    float e[9];
    float mx = 0.0f;
#pragma unroll
    for (int s = 0; s < 9; ++s) { e[s] = ls[SC + lane * 9 + s]; mx = fmaxf(mx, e[s]); }
    float den = 72.0f * __expf(-mx);
#pragma unroll
    for (int s = 0; s < 9; ++s) {
      e[s] = __expf(e[s] - mx);
      den += e[s];
      ls[SC + lane * 9 + s] = e[s];
    }
    ls[SC + 81 + lane] = 1.0f / den;
  }
  wsync();

  // P3d: zrow = attn-out (via vo) + residual; shared row t=9
  for (int idx = lane; idx < 110; idx += 64) {
    int t = idx / 11, c = idx - (idx / 11) * 11;
    float a = 0.f;
    if (t < 9) {
#pragma unroll
      for (int s = 0; s < 9; ++s) a += ls[SC + t * 9 + s] * ls[VO + s * 11 + c];
      a = a * ls[SC + 81 + t] + ls[F9 + idx];
    } else {
#pragma unroll
      for (int s = 0; s < 9; ++s) a += ls[VO + s * 11 + c];
      a *= (1.0f / 81.0f);
    }
    ls[ZR + idx] = a;
  }
  wsync();

  // P4s: per-row LN1 + FF + LN2 in registers (lanes 0-9) -> FET[c][t]
  if (lane < 10) {
    float row[11];
#pragma unroll
    for (int c = 0; c < 11; ++c) row[c] = ls[ZR + lane * 11 + c];
    float s1 = 0.f, s2 = 0.f;
#pragma unroll
    for (int c = 0; c < 11; ++c) { s1 += row[c]; s2 += row[c] * row[c]; }
    float mu = s1 * (1.0f / 11.0f);
    float rs = 1.0f / sqrtf(s2 * (1.0f / 11.0f) - mu * mu + 1e-5f);
    float h = 0.f;
#pragma unroll
    for (int c = 0; c < 11; ++c) {
      row[c] = (row[c] - mu) * rs * enc_ln1[c];
      h += row[c] * enc_lin1[c];
    }
    h = fmaxf(h, 0.f);
    float t1 = 0.f, t2 = 0.f;
#pragma unroll
    for (int c = 0; c < 11; ++c) {
      row[c] += h * enc_lin2[c];
      t1 += row[c]; t2 += row[c] * row[c];
    }
    float mu2 = t1 * (1.0f / 11.0f);
    float rs2 = 1.0f / sqrtf(t2 * (1.0f / 11.0f) - mu2 * mu2 + 1e-5f);
#pragma unroll
    for (int c = 0; c < 11; ++c)
      ls[FET + c * 12 + lane] = (row[c] - mu2) * rs2 * enc_ln2[c];
  }
  wsync();

  // P5 (register): lane computes K-row (grp0) / V-row (grp1) for head hh
  const int hh = lane & 31, grp = lane >> 5;
  float kv[11];
  {
    const float* Gb = grp ? G_v : G_k;
    float gr[10];
#pragma unroll
    for (int t = 0; t < 10; ++t) gr[t] = Gb[t * 32 + hh];
#pragma unroll
    for (int cc = 0; cc < 11; ++cc) {
      const float4* fr = (const float4*)(ls + FET + cc * 12);
      float4 a = fr[0], b4 = fr[1], c4 = fr[2];
      float fe[10] = {a.x, a.y, a.z, a.w, b4.x, b4.y, b4.z, b4.w, c4.x, c4.y};
      float s = 0.f;
#pragma unroll
      for (int t = 0; t < 10; ++t) s += fe[t] * gr[t];
      kv[cc] = s;
    }
  }
  // exchange halves: every lane ends with kk = K-row, vv = V-row for head hh
  float kk[11], vv[11];
#pragma unroll
  for (int cc = 0; cc < 11; ++cc) {
    float o = __shfl_xor(kv[cc], 32);
    kk[cc] = grp ? o : kv[cc];
    vv[cc] = grp ? kv[cc] : o;
  }

  // P6 (register): cross-attn (32 heads dim-1, Lq=10, Lk=11) -> oca @ OC
#pragma unroll
  for (int i = 0; i < 5; ++i) {
    int t = grp * 5 + i;
    float q = qcag[t * 32 + hh];
    float sc[11];
    float mx = q * kk[0];
    sc[0] = mx;
#pragma unroll
    for (int s = 1; s < 11; ++s) { sc[s] = q * kk[s]; mx = fmaxf(mx, sc[s]); }
    float den = 0.f, acc = 0.f;
#pragma unroll
    for (int s = 0; s < 11; ++s) {
      float e = __expf(sc[s] - mx);
      den += e;
      acc += e * vv[s];
    }
    ls[OC + t * 32 + hh] = acc / den;
  }
  wsync();

  // P7a: out-proj + residual + LN2 + FF + LN3 -> z rows @ ZB  (verbatim r3)
  for (int k = 0; k < 5; ++k) {
    int t = 2 * k + grp;
    int c = hh;
    float zacc = 0.f;
    const float4* wrow = (const float4*)(dec_ca_out + c * 32);
    const float4* orow = (const float4*)(ls + OC + t * 32);
#pragma unroll
    for (int h4 = 0; h4 < 8; ++h4) {
      float4 o4 = orow[h4];
      float4 w4 = wrow[h4];
      zacc += o4.x * w4.x + o4.y * w4.y + o4.z * w4.z + o4.w * w4.w;
    }
    float z = y1g[t * 32 + c] + zacc;
    {
      float s1 = gsum32(z), s2 = gsum32(z * z);
      float mu = s1 * (1.0f / 32.0f);
      z = (z - mu) * (1.0f / sqrtf(s2 * (1.0f / 32.0f) - mu * mu + 1e-5f)) * dec_ln2v[c];
    }
    {
      float d1 = gsum32(z * dec_lin1[c]);
      z += fmaxf(d1, 0.f) * dec_lin2[c];
    }
    {
      float s1 = gsum32(z), s2 = gsum32(z * z);
      float mu = s1 * (1.0f / 32.0f);
      z = (z - mu) * (1.0f / sqrtf(s2 * (1.0f / 32.0f) - mu * mu + 1e-5f)) * dec_ln3v[c];
    }
    ls[ZB + t * 32 + c] = z;
  }
  wsync();

  // P7b: head layer 1: relu(z @ W_d0^T) -> OC[0..79]
  for (int idx = lane; idx < 80; idx += 64) {
    int t = idx >> 3, m = idx & 7;
    const float4* arow = (const float4*)(W_d0 + m * 32);
    const float4* zrow4 = (const float4*)(ls + ZB + t * 32);
    float d = 0.f;
#pragma unroll
    for (int q4 = 0; q4 < 8; ++q4) {
      float4 a4 = arow[q4];
      float4 z4 = zrow4[q4];
      d += a4.x * z4.x + a4.y * z4.y + a4.z * z4.z + a4.w * z4.w;
    }
    ls[OC + idx] = fmaxf(d, 0.f);
  }
  wsync();

  // P7c: head layer 2 + store
  if (lane < 10) {
    float r = 0.f;
#pragma unroll
    for (int m = 0; m < 8; ++m) r += ls[OC + lane * 8 + m] * W_d1[m];
    out[((n * 10 + lane) * 30 + pi) * 30 + pj] = r;
  }
}

// ---------------------------------------------------------------------------
extern "C" void kernel_launch(void* const* d_in, const int* in_sizes, int n_in,
                              void* d_out, int out_size, void* d_ws, size_t ws_size,
                              hipStream_t stream) {
  (void)in_sizes; (void)n_in; (void)out_size; (void)ws_size;
  const float* x          = (const float*)d_in[0];
  const float* Vf         = (const float*)d_in[1];
  const float* enc_in     = (const float*)d_in[2];
  const float* enc_outw   = (const float*)d_in[3];
  const float* enc_lin1   = (const float*)d_in[4];
  const float* enc_lin2   = (const float*)d_in[5];
  const float* enc_ln1    = (const float*)d_in[6];
  const float* enc_ln2    = (const float*)d_in[7];
  const float* ffV_w      = (const float*)d_in[8];
  const float* dec_sa_in  = (const float*)d_in[9];
  const float* dec_sa_out = (const float*)d_in[10];
  const float* dec_ca_in  = (const float*)d_in[11];
  const float* dec_ca_out = (const float*)d_in[12];
  const float* dec_lin1   = (const float*)d_in[13];
  const float* dec_lin2   = (const float*)d_in[14];
  const float* dec_ln1    = (const float*)d_in[15];
  const float* dec_ln2    = (const float*)d_in[16];
  const float* dec_ln3    = (const float*)d_in[17];
  const float* W_d0       = (const float*)d_in[18];
  const float* W_d1       = (const float*)d_in[19];
  float* out = (float*)d_out;

  float* ws    = (float*)d_ws;
  float* M_enc = ws;            // 121 -> pad 128
  float* WVO   = ws + 128;      // 121 -> pad 128
  float* G_k   = ws + 256;      // 320
  float* G_v   = ws + 576;      // 320
  float* y1    = ws + 896;      // 320
  float* qca   = ws + 1216;     // 320   (total 1536 floats = 6 KiB)

  hipLaunchKernelGGL(precompute_kernel, dim3(2), dim3(256), 0, stream,
                     Vf, enc_in, enc_outw, ffV_w, dec_sa_in, dec_sa_out,
                     dec_ln1, dec_ca_in, M_enc, WVO, G_k, G_v, y1, qca);

  hipLaunchKernelGGL(pixel_main_kernel, dim3(3600), dim3(256), 0, stream,
                     x, M_enc, WVO, enc_lin1, enc_lin2, enc_ln1, enc_ln2,
                     G_k, G_v, y1, qca, dec_ca_out, dec_lin1, dec_lin2,
                     dec_ln2, dec_ln3, W_d0, W_d1, out);
}